// Round 1
// baseline (28263.715 us; speedup 1.0000x reference)
//
#include <hip/hip_runtime.h>
#include <math.h>

#define D_DIM 1024
#define E_NUM 8
#define H_DIM 2730
#define N_TOK 8192

#define TM 32            // tokens per FFN block
#define HC 128           // H-chunk
#define DQ 256           // d-quarter staged in LDS
#define FFN_THREADS 512
#define NTILES (N_TOK / TM)   // 256 tiles per expert (worst case)

// ---------------------------------------------------------------------------
// Routing: one wave (64 lanes) per token. Computes logits = x . Wr (8 dots of
// length 1024), softmax, top-2, and appends (token, gate) to per-expert lists.
// ---------------------------------------------------------------------------
__global__ __launch_bounds__(256) void route_kernel(
    const float* __restrict__ x, const float* __restrict__ Wr,
    int* __restrict__ counts, int* __restrict__ tok_idx, float* __restrict__ tok_gate)
{
    const int gtid = blockIdx.x * blockDim.x + threadIdx.x;
    const int tok  = gtid >> 6;
    const int lane = gtid & 63;
    if (tok >= N_TOK) return;

    const float* xr = x + (size_t)tok * D_DIM + lane * 16;
    float acc[E_NUM];
#pragma unroll
    for (int e = 0; e < E_NUM; ++e) acc[e] = 0.f;

#pragma unroll
    for (int i = 0; i < 16; ++i) {
        const float xv = xr[i];
        const float* wr = Wr + (size_t)(lane * 16 + i) * E_NUM;
#pragma unroll
        for (int e = 0; e < E_NUM; ++e) acc[e] = fmaf(xv, wr[e], acc[e]);
    }
    // full-wave butterfly reduce for all 8 logits
#pragma unroll
    for (int off = 32; off >= 1; off >>= 1) {
#pragma unroll
        for (int e = 0; e < E_NUM; ++e) acc[e] += __shfl_xor(acc[e], off, 64);
    }

    if (lane == 0) {
        float m = acc[0];
#pragma unroll
        for (int e = 1; e < E_NUM; ++e) m = fmaxf(m, acc[e]);
        float p[E_NUM];
        float s = 0.f;
#pragma unroll
        for (int e = 0; e < E_NUM; ++e) { p[e] = expf(acc[e] - m); s += p[e]; }
        const float inv = 1.f / s;

        // top-1 (first index wins ties, matching jax.lax.top_k)
        int i0 = 0; float v0 = p[0];
#pragma unroll
        for (int e = 1; e < E_NUM; ++e) { if (p[e] > v0) { v0 = p[e]; i0 = e; } }
        // top-2
        int i1 = -1; float v1 = -1.f;
#pragma unroll
        for (int e = 0; e < E_NUM; ++e) { if (e != i0 && p[e] > v1) { v1 = p[e]; i1 = e; } }

        int s0 = atomicAdd(&counts[i0], 1);
        tok_idx [i0 * N_TOK + s0] = tok;
        tok_gate[i0 * N_TOK + s0] = v0 * inv;
        int s1 = atomicAdd(&counts[i1], 1);
        tok_idx [i1 * N_TOK + s1] = tok;
        tok_gate[i1 * N_TOK + s1] = v1 * inv;
    }
}

// ---------------------------------------------------------------------------
// Fused expert FFN: block = (expert e, tile of TM=32 gathered tokens).
// For each H-chunk of 128: a1 = x@W1c, a3 = x@W3c  (x staged in LDS in
// d-quarters, transposed for broadcast b128 reads), h = silu(a1)*a3 -> LDS,
// out_acc += h @ W2c (4 tokens x 16 cols per thread in registers).
// Epilogue: out[token] += gate * out_acc via atomicAdd (each token has
// exactly 2 experts; out is zeroed before launch).
// ---------------------------------------------------------------------------
__global__ __launch_bounds__(FFN_THREADS, 4) void ffn_kernel(
    const float* __restrict__ x,
    const float* __restrict__ W1, const float* __restrict__ W2,
    const float* __restrict__ W3,
    const int* __restrict__ counts, const int* __restrict__ tok_idx,
    const float* __restrict__ tok_gate,
    float* __restrict__ out)
{
    __shared__ float xs[DQ][TM + 4];   // 256 x 36 x 4B = 36 KB (transposed x quarter)
    __shared__ float hs[HC][TM + 4];   // 128 x 36 x 4B = 18 KB (transposed h tile)
    __shared__ int   s_tok[TM];
    __shared__ float s_gate[TM];

    const int e    = blockIdx.x / NTILES;
    const int tile = blockIdx.x % NTILES;
    const int cnt  = counts[e];
    const int base = tile * TM;
    if (base >= cnt) return;   // uniform early-exit (no barriers crossed)

    const int tid  = threadIdx.x;
    const int lane = tid & 63;
    const int grp  = tid >> 6;     // wave id 0..7
    const int g4   = grp * 4;      // this wave's 4-token group base

    if (tid < TM) {
        const int slot = base + tid;
        const bool v = slot < cnt;
        s_tok[tid]  = v ? tok_idx [(size_t)e * N_TOK + slot] : 0;
        s_gate[tid] = v ? tok_gate[(size_t)e * N_TOK + slot] : 0.f;
    }

    const float* __restrict__ W1e = W1 + (size_t)e * D_DIM * H_DIM;
    const float* __restrict__ W3e = W3 + (size_t)e * D_DIM * H_DIM;
    const float* __restrict__ W2e = W2 + (size_t)e * H_DIM * D_DIM;

    float oacc[4][16];
#pragma unroll
    for (int t = 0; t < 4; ++t)
#pragma unroll
        for (int k = 0; k < 16; ++k) oacc[t][k] = 0.f;

    const int c0 = 2 * lane;   // step-1 column pair within the H-chunk

    for (int hb = 0; hb < H_DIM; hb += HC) {
        const int hc = min(HC, H_DIM - hb);   // 128, last chunk 42

        float a1[4][2], a3[4][2];
#pragma unroll
        for (int t = 0; t < 4; ++t) {
            a1[t][0] = 0.f; a1[t][1] = 0.f;
            a3[t][0] = 0.f; a3[t][1] = 0.f;
        }

        for (int dq = 0; dq < D_DIM; dq += DQ) {
            __syncthreads();   // previous readers of xs/hs done
            // stage x quarter, transposed: wave grp loads its own 4 token rows
#pragma unroll
            for (int r = 0; r < 4; ++r) {
                const int t = g4 + r;
                const float4 v = *(const float4*)(x + (size_t)s_tok[t] * D_DIM + dq + lane * 4);
                xs[lane * 4 + 0][t] = v.x;
                xs[lane * 4 + 1][t] = v.y;
                xs[lane * 4 + 2][t] = v.z;
                xs[lane * 4 + 3][t] = v.w;
            }
            __syncthreads();

            if (hc == HC) {
                const float* w1p = W1e + (size_t)dq * H_DIM + hb + c0;
                const float* w3p = W3e + (size_t)dq * H_DIM + hb + c0;
#pragma unroll 4
                for (int d = 0; d < DQ; ++d) {
                    const float2 w1 = *(const float2*)w1p;
                    const float2 w3 = *(const float2*)w3p;
                    const float4 xv = *(const float4*)&xs[d][g4];   // wave-broadcast
                    const float xvv[4] = {xv.x, xv.y, xv.z, xv.w};
#pragma unroll
                    for (int t = 0; t < 4; ++t) {
                        a1[t][0] = fmaf(xvv[t], w1.x, a1[t][0]);
                        a1[t][1] = fmaf(xvv[t], w1.y, a1[t][1]);
                        a3[t][0] = fmaf(xvv[t], w3.x, a3[t][0]);
                        a3[t][1] = fmaf(xvv[t], w3.y, a3[t][1]);
                    }
                    w1p += H_DIM; w3p += H_DIM;
                }
            } else {
                // tail chunk (hc = 42, even): clamp address, mask value
                const int   c0c = min(c0, hc - 2);
                const float msk = (c0 < hc) ? 1.f : 0.f;
                const float* w1p = W1e + (size_t)dq * H_DIM + hb + c0c;
                const float* w3p = W3e + (size_t)dq * H_DIM + hb + c0c;
#pragma unroll 4
                for (int d = 0; d < DQ; ++d) {
                    float2 w1 = *(const float2*)w1p;
                    float2 w3 = *(const float2*)w3p;
                    w1.x *= msk; w1.y *= msk; w3.x *= msk; w3.y *= msk;
                    const float4 xv = *(const float4*)&xs[d][g4];
                    const float xvv[4] = {xv.x, xv.y, xv.z, xv.w};
#pragma unroll
                    for (int t = 0; t < 4; ++t) {
                        a1[t][0] = fmaf(xvv[t], w1.x, a1[t][0]);
                        a1[t][1] = fmaf(xvv[t], w1.y, a1[t][1]);
                        a3[t][0] = fmaf(xvv[t], w3.x, a3[t][0]);
                        a3[t][1] = fmaf(xvv[t], w3.y, a3[t][1]);
                    }
                    w1p += H_DIM; w3p += H_DIM;
                }
            }
        }

        // silu(a1)*a3 -> hs (transposed)
#pragma unroll
        for (int t = 0; t < 4; ++t) {
#pragma unroll
            for (int c = 0; c < 2; ++c) {
                const float v1 = a1[t][c];
                const float hv = (v1 / (1.f + expf(-v1))) * a3[t][c];
                hs[c0 + c][g4 + t] = hv;
            }
        }
        __syncthreads();

        // step 2: out_acc += h @ W2c ; thread owns 4 tokens x cols {lane*4+q*256+c}
        const float* w2p = W2e + (size_t)hb * D_DIM + lane * 4;
        for (int j = 0; j < hc; ++j) {
            const float4 hv = *(const float4*)&hs[j][g4];   // wave-broadcast
            const float hvv[4] = {hv.x, hv.y, hv.z, hv.w};
#pragma unroll
            for (int q = 0; q < 4; ++q) {
                const float4 w = *(const float4*)(w2p + q * 256);
#pragma unroll
                for (int t = 0; t < 4; ++t) {
                    oacc[t][q * 4 + 0] = fmaf(hvv[t], w.x, oacc[t][q * 4 + 0]);
                    oacc[t][q * 4 + 1] = fmaf(hvv[t], w.y, oacc[t][q * 4 + 1]);
                    oacc[t][q * 4 + 2] = fmaf(hvv[t], w.z, oacc[t][q * 4 + 2]);
                    oacc[t][q * 4 + 3] = fmaf(hvv[t], w.w, oacc[t][q * 4 + 3]);
                }
            }
            w2p += D_DIM;
        }
        __syncthreads();
    }

    // epilogue: out[token] += gate * acc
#pragma unroll
    for (int t = 0; t < 4; ++t) {
        const float g = s_gate[g4 + t];
        if (g != 0.f) {
            float* op = out + (size_t)s_tok[g4 + t] * D_DIM + lane * 4;
#pragma unroll
            for (int q = 0; q < 4; ++q) {
#pragma unroll
                for (int c = 0; c < 4; ++c) {
                    atomicAdd(op + q * 256 + c, g * oacc[t][q * 4 + c]);
                }
            }
        }
    }
}

// ---------------------------------------------------------------------------
extern "C" void kernel_launch(void* const* d_in, const int* in_sizes, int n_in,
                              void* d_out, int out_size, void* d_ws, size_t ws_size,
                              hipStream_t stream)
{
    const float* x  = (const float*)d_in[0];
    const float* Wr = (const float*)d_in[1];
    const float* W1 = (const float*)d_in[2];
    const float* W2 = (const float*)d_in[3];
    const float* W3 = (const float*)d_in[4];
    float* out = (float*)d_out;

    // ws layout: [counts: 8 ints (padded to 64B)] [tok_idx: E*N ints] [tok_gate: E*N floats]
    int*   counts   = (int*)d_ws;
    int*   tok_idx  = (int*)((char*)d_ws + 64);
    float* tok_gate = (float*)((char*)d_ws + 64 + (size_t)E_NUM * N_TOK * sizeof(int));

    hipMemsetAsync(counts, 0, 64, stream);
    hipMemsetAsync(d_out, 0, (size_t)N_TOK * D_DIM * sizeof(float), stream);

    route_kernel<<<N_TOK / 4, 256, 0, stream>>>(x, Wr, counts, tok_idx, tok_gate);

    ffn_kernel<<<E_NUM * NTILES, FFN_THREADS, 0, stream>>>(
        x, W1, W2, W3, counts, tok_idx, tok_gate, out);
}

// Round 2
// 16778.241 us; speedup vs baseline: 1.6845x; 1.6845x over previous
//
#include <hip/hip_runtime.h>
#include <math.h>

#define D_DIM 1024
#define E_NUM 8
#define H_DIM 2730
#define N_TOK 8192

#define TM 32            // tokens per FFN block
#define HC 256           // H-chunk (11 chunks, last = 170)
#define DQ 128           // d-slice staged in LDS
#define FFN_THREADS 512
#define NTILES (N_TOK / TM)   // 256 tiles per expert (worst case)

// ---------------------------------------------------------------------------
// Routing: one wave per token. logits = x.Wr, softmax, top-2, append to
// per-expert compacted lists in workspace.
// ---------------------------------------------------------------------------
__global__ __launch_bounds__(256) void route_kernel(
    const float* __restrict__ x, const float* __restrict__ Wr,
    int* __restrict__ counts, int* __restrict__ tok_idx, float* __restrict__ tok_gate)
{
    const int gtid = blockIdx.x * blockDim.x + threadIdx.x;
    const int tok  = gtid >> 6;
    const int lane = gtid & 63;
    if (tok >= N_TOK) return;

    const float* xr = x + (size_t)tok * D_DIM + lane * 16;
    float acc[E_NUM];
#pragma unroll
    for (int e = 0; e < E_NUM; ++e) acc[e] = 0.f;

#pragma unroll
    for (int i = 0; i < 16; ++i) {
        const float xv = xr[i];
        const float* wr = Wr + (size_t)(lane * 16 + i) * E_NUM;
#pragma unroll
        for (int e = 0; e < E_NUM; ++e) acc[e] = fmaf(xv, wr[e], acc[e]);
    }
#pragma unroll
    for (int off = 32; off >= 1; off >>= 1) {
#pragma unroll
        for (int e = 0; e < E_NUM; ++e) acc[e] += __shfl_xor(acc[e], off, 64);
    }

    if (lane == 0) {
        float m = acc[0];
#pragma unroll
        for (int e = 1; e < E_NUM; ++e) m = fmaxf(m, acc[e]);
        float p[E_NUM];
        float s = 0.f;
#pragma unroll
        for (int e = 0; e < E_NUM; ++e) { p[e] = expf(acc[e] - m); s += p[e]; }
        const float inv = 1.f / s;

        int i0 = 0; float v0 = p[0];
#pragma unroll
        for (int e = 1; e < E_NUM; ++e) { if (p[e] > v0) { v0 = p[e]; i0 = e; } }
        int i1 = -1; float v1 = -1.f;
#pragma unroll
        for (int e = 0; e < E_NUM; ++e) { if (e != i0 && p[e] > v1) { v1 = p[e]; i1 = e; } }

        int s0 = atomicAdd(&counts[i0], 1);
        tok_idx [i0 * N_TOK + s0] = tok;
        tok_gate[i0 * N_TOK + s0] = v0 * inv;
        int s1 = atomicAdd(&counts[i1], 1);
        tok_idx [i1 * N_TOK + s1] = tok;
        tok_gate[i1 * N_TOK + s1] = v1 * inv;
    }
}

// ---------------------------------------------------------------------------
// Fused expert FFN. Block = (expert, 32 gathered tokens). Per H-chunk of 256:
//   step 1: a1 = x@W1c, a3 = x@W3c  (x staged in LDS in 128-wide d-slices;
//           thread owns 4 tokens x 4 consecutive cols, float4 weight loads,
//           batched 8 loads per 4 d-steps for latency hiding)
//   silu(a1)*a3 -> hs (natural layout, conflict-free float4 writes)
//   step 2: oacc += hs @ W2c  (thread owns 4 tokens x 16 out-cols)
// Epilogue: out[token] += gate * oacc via atomicAdd (out pre-zeroed).
// ---------------------------------------------------------------------------
__global__ __launch_bounds__(FFN_THREADS, 3) void ffn_kernel(
    const float* __restrict__ x,
    const float* __restrict__ W1, const float* __restrict__ W2,
    const float* __restrict__ W3,
    const int* __restrict__ counts, const int* __restrict__ tok_idx,
    const float* __restrict__ tok_gate,
    float* __restrict__ out)
{
    __shared__ float xs[TM][DQ + 4];   // 32 x 132 x 4B = 16.9 KB
    __shared__ float hs[TM][HC + 4];   // 32 x 260 x 4B = 33.3 KB
    __shared__ int   s_tok[TM];
    __shared__ float s_gate[TM];

    const int e    = blockIdx.x / NTILES;
    const int tile = blockIdx.x % NTILES;
    const int cnt  = counts[e];
    const int base = tile * TM;
    if (base >= cnt) return;   // uniform early-exit, before any barrier

    const int tid  = threadIdx.x;
    const int lane = tid & 63;
    const int grp  = tid >> 6;     // wave id 0..7
    const int g4   = grp * 4;      // this wave's 4-token group
    const int c0   = lane << 2;    // 4 consecutive cols in the H-chunk

    if (tid < TM) {
        const int slot = base + tid;
        const bool v = slot < cnt;
        s_tok[tid]  = v ? tok_idx [(size_t)e * N_TOK + slot] : 0;
        s_gate[tid] = v ? tok_gate[(size_t)e * N_TOK + slot] : 0.f;
    }
    __syncthreads();

    // staging assignment: thread stages 8 floats of row (tid>>4)
    const int   st_row  = tid >> 4;          // 0..31
    const int   st_col  = (tid & 15) << 3;   // 0..120
    const float* st_src = x + (size_t)s_tok[st_row] * D_DIM + st_col;

    const float* __restrict__ W1e = W1 + (size_t)e * D_DIM * H_DIM;
    const float* __restrict__ W3e = W3 + (size_t)e * D_DIM * H_DIM;
    const float* __restrict__ W2e = W2 + (size_t)e * H_DIM * D_DIM;

    float oacc[4][16];
#pragma unroll
    for (int t = 0; t < 4; ++t)
#pragma unroll
        for (int k = 0; k < 16; ++k) oacc[t][k] = 0.f;

    for (int hb = 0; hb < H_DIM; hb += HC) {
        const int hc = min(HC, H_DIM - hb);   // 256, last chunk 170

        float a1[4][4], a3[4][4];
#pragma unroll
        for (int t = 0; t < 4; ++t)
#pragma unroll
            for (int c = 0; c < 4; ++c) { a1[t][c] = 0.f; a3[t][c] = 0.f; }

        for (int dq = 0; dq < D_DIM; dq += DQ) {
            // issue x loads BEFORE the barrier so latency overlaps the drain
            const float4 v0 = *(const float4*)(st_src + dq);
            const float4 v1 = *(const float4*)(st_src + dq + 4);
            __syncthreads();   // previous readers of xs done
            *(float4*)&xs[st_row][st_col]     = v0;
            *(float4*)&xs[st_row][st_col + 4] = v1;
            __syncthreads();

            if (hc == HC) {
                // fast path: no masking anywhere
                const float* w1p = W1e + (size_t)dq * H_DIM + hb + c0;
                const float* w3p = W3e + (size_t)dq * H_DIM + hb + c0;
#pragma unroll 2
                for (int d0 = 0; d0 < DQ; d0 += 4) {
                    float4 w1r[4], w3r[4];
#pragma unroll
                    for (int i = 0; i < 4; ++i) {
                        w1r[i] = *(const float4*)(w1p + (size_t)i * H_DIM);
                        w3r[i] = *(const float4*)(w3p + (size_t)i * H_DIM);
                    }
                    w1p += 4 * H_DIM; w3p += 4 * H_DIM;
                    float xarr[4][4];
#pragma unroll
                    for (int t = 0; t < 4; ++t) {
                        const float4 v = *(const float4*)&xs[g4 + t][d0];  // broadcast
                        xarr[t][0] = v.x; xarr[t][1] = v.y;
                        xarr[t][2] = v.z; xarr[t][3] = v.w;
                    }
#pragma unroll
                    for (int i = 0; i < 4; ++i) {
                        const float4 w1 = w1r[i], w3 = w3r[i];
#pragma unroll
                        for (int t = 0; t < 4; ++t) {
                            const float xv = xarr[t][i];
                            a1[t][0] = fmaf(xv, w1.x, a1[t][0]);
                            a1[t][1] = fmaf(xv, w1.y, a1[t][1]);
                            a1[t][2] = fmaf(xv, w1.z, a1[t][2]);
                            a1[t][3] = fmaf(xv, w1.w, a1[t][3]);
                            a3[t][0] = fmaf(xv, w3.x, a3[t][0]);
                            a3[t][1] = fmaf(xv, w3.y, a3[t][1]);
                            a3[t][2] = fmaf(xv, w3.z, a3[t][2]);
                            a3[t][3] = fmaf(xv, w3.w, a3[t][3]);
                        }
                    }
                }
            } else {
                // tail chunk (hc=170): masked scalar loads, clamped addresses
                int   cs[4]; float msk[4];
#pragma unroll
                for (int ci = 0; ci < 4; ++ci) {
                    const int col = c0 + ci;
                    const bool ok = col < hc;
                    cs[ci]  = ok ? col : 0;
                    msk[ci] = ok ? 1.f : 0.f;
                }
                const float* w1row = W1e + (size_t)dq * H_DIM + hb;
                const float* w3row = W3e + (size_t)dq * H_DIM + hb;
#pragma unroll 4
                for (int d0 = 0; d0 < DQ; ++d0) {
                    float w1v[4], w3v[4];
#pragma unroll
                    for (int ci = 0; ci < 4; ++ci) {
                        w1v[ci] = w1row[cs[ci]] * msk[ci];
                        w3v[ci] = w3row[cs[ci]] * msk[ci];
                    }
                    w1row += H_DIM; w3row += H_DIM;
#pragma unroll
                    for (int t = 0; t < 4; ++t) {
                        const float xv = xs[g4 + t][d0];
#pragma unroll
                        for (int ci = 0; ci < 4; ++ci) {
                            a1[t][ci] = fmaf(xv, w1v[ci], a1[t][ci]);
                            a3[t][ci] = fmaf(xv, w3v[ci], a3[t][ci]);
                        }
                    }
                }
            }
        }

        // h = silu(a1) * a3 -> hs (cols >= hc get 0, never read)
#pragma unroll
        for (int t = 0; t < 4; ++t) {
            float4 hv;
            hv.x = (a1[t][0] / (1.f + __expf(-a1[t][0]))) * a3[t][0];
            hv.y = (a1[t][1] / (1.f + __expf(-a1[t][1]))) * a3[t][1];
            hv.z = (a1[t][2] / (1.f + __expf(-a1[t][2]))) * a3[t][2];
            hv.w = (a1[t][3] / (1.f + __expf(-a1[t][3]))) * a3[t][3];
            *(float4*)&hs[g4 + t][c0] = hv;
        }
        __syncthreads();

        // step 2: oacc += hs @ W2c
        const float* w2p = W2e + (size_t)hb * D_DIM + (lane << 2);
#pragma unroll 2
        for (int j0 = 0; j0 < hc; j0 += 2) {
            float2 hv[4];
#pragma unroll
            for (int t = 0; t < 4; ++t) hv[t] = *(const float2*)&hs[g4 + t][j0];  // broadcast
#pragma unroll
            for (int jj = 0; jj < 2; ++jj) {
                float4 w2r[4];
#pragma unroll
                for (int q = 0; q < 4; ++q) w2r[q] = *(const float4*)(w2p + (q << 8));
                w2p += D_DIM;
#pragma unroll
                for (int t = 0; t < 4; ++t) {
                    const float hvv = jj ? hv[t].y : hv[t].x;
#pragma unroll
                    for (int q = 0; q < 4; ++q) {
                        oacc[t][q * 4 + 0] = fmaf(hvv, w2r[q].x, oacc[t][q * 4 + 0]);
                        oacc[t][q * 4 + 1] = fmaf(hvv, w2r[q].y, oacc[t][q * 4 + 1]);
                        oacc[t][q * 4 + 2] = fmaf(hvv, w2r[q].z, oacc[t][q * 4 + 2]);
                        oacc[t][q * 4 + 3] = fmaf(hvv, w2r[q].w, oacc[t][q * 4 + 3]);
                    }
                }
            }
        }
        // no barrier needed here: next chunk's hs write is after its dq-loop barriers
    }

    // epilogue: out[token] += gate * oacc
#pragma unroll
    for (int t = 0; t < 4; ++t) {
        const float g = s_gate[g4 + t];
        if (g != 0.f) {
            float* op = out + (size_t)s_tok[g4 + t] * D_DIM + (lane << 2);
#pragma unroll
            for (int q = 0; q < 4; ++q) {
#pragma unroll
                for (int c = 0; c < 4; ++c) {
                    atomicAdd(op + (q << 8) + c, g * oacc[t][q * 4 + c]);
                }
            }
        }
    }
}

// ---------------------------------------------------------------------------
extern "C" void kernel_launch(void* const* d_in, const int* in_sizes, int n_in,
                              void* d_out, int out_size, void* d_ws, size_t ws_size,
                              hipStream_t stream)
{
    const float* x  = (const float*)d_in[0];
    const float* Wr = (const float*)d_in[1];
    const float* W1 = (const float*)d_in[2];
    const float* W2 = (const float*)d_in[3];
    const float* W3 = (const float*)d_in[4];
    float* out = (float*)d_out;

    int*   counts   = (int*)d_ws;
    int*   tok_idx  = (int*)((char*)d_ws + 64);
    float* tok_gate = (float*)((char*)d_ws + 64 + (size_t)E_NUM * N_TOK * sizeof(int));

    hipMemsetAsync(counts, 0, 64, stream);
    hipMemsetAsync(d_out, 0, (size_t)N_TOK * D_DIM * sizeof(float), stream);

    route_kernel<<<N_TOK / 4, 256, 0, stream>>>(x, Wr, counts, tok_idx, tok_gate);

    ffn_kernel<<<E_NUM * NTILES, FFN_THREADS, 0, stream>>>(
        x, W1, W2, W3, counts, tok_idx, tok_gate, out);
}